// Round 9
// baseline (64.209 us; speedup 1.0000x reference)
//
#include <hip/hip_runtime.h>

// Fused: depthwise(1x3, 64ch) -> pair-sum (64->32ch) -> conv3x3 (32->64ch)
// x: (1,64,56,56) f32, w_conv: (64,32,3,3,1), w_dw: (64,3,1), out: (1,64,56,56)
//
// Grid (56 rows, 4 og of 16 out-ch). Block 256. Single barrier.
// Phase A (unchanged, T14 issue-early): all A2 x-loads + dw-tap loads issued
// into registers FIRST; A1 weight staging (float4 loads + LDS scatter) runs
// under that latency; A2 computes t5 -> st5[96][68]; barrier.
// Phase B (new split): ccq 8-way x 4 ol x 8 w per thread -> 336 LDS wave-ops
// (was 480), t5 re-read 4x (was 8x), VALU still spread over all 4 SIMDs;
// 3-level shfl_xor reduce.

#define HH 56
#define WW 56
#define CIN 64
#define CMID 32
#define OG 16
#define CHW (HH * WW)
#define T5STR 68   // 68 % 32 == 4: adjacent rows offset 4 banks; 16B-aligned
#define WSTR 388   // 32*3*4 + 4 pad; 388 % 32 == 4 -> ol-stride offsets banks

__global__ __launch_bounds__(256) void fused_dw_sum_conv(
    const float* __restrict__ x,
    const float* __restrict__ wc,
    const float* __restrict__ wd,
    float* __restrict__ out)
{
    __shared__ __align__(16) float st5[3 * CMID * T5STR];  // 26112 B
    __shared__ __align__(16) float swc[OG * WSTR];         // 24832 B

    const int tid = threadIdx.x;
    const int h   = blockIdx.x;
    const int og  = blockIdx.y;

    // ---- stage 1: ISSUE all A2 global loads into registers ----
    float2 L0[6], L1[6], TA[6], TB[6], TC[6];
    float4 M0[6], M1[6];
    #pragma unroll
    for (int k = 0; k < 6; ++k) {
        L0[k] = make_float2(0.f, 0.f); L1[k] = make_float2(0.f, 0.f);
        M0[k] = make_float4(0.f, 0.f, 0.f, 0.f);
        M1[k] = make_float4(0.f, 0.f, 0.f, 0.f);
        int idx = tid + k * 256;
        if (idx < 3 * CMID * 15) {
            int r   = idx / (CMID * 15);
            int rem = idx - r * (CMID * 15);
            int cc  = rem / 15;
            int wq  = rem - cc * 15;
            int hr  = h - 1 + r;
            const float* dwp = wd + 6 * cc;      // taps: valid regardless of hr
            TA[k] = *(const float2*)(dwp);       // d0[0], d0[1]
            TB[k] = *(const float2*)(dwp + 2);   // d0[2], d1[0]
            TC[k] = *(const float2*)(dwp + 4);   // d1[1], d1[2]
            if ((unsigned)hr < HH) {
                int ws0  = 4 * wq;
                int lcol = (wq == 0)  ? 0  : ws0 - 2;   // clamped, 8B-aligned
                int mcol = (wq == 14) ? 48 : ws0;       // clamped, 16B-aligned
                const float* p0 = x + (2 * cc) * CHW + hr * WW;
                const float* p1 = p0 + CHW;
                L0[k] = *(const float2*)(p0 + lcol);
                L1[k] = *(const float2*)(p1 + lcol);
                M0[k] = *(const float4*)(p0 + mcol);
                M1[k] = *(const float4*)(p1 + mcol);
            }
        }
    }

    // ---- stage 2: A1 weight staging (runs under x-load latency) ----
    #pragma unroll
    for (int k = 0; k < 5; ++k) {
        int q = tid + k * 256;          // quad index, 1152 total
        if (q < 1152) {
            float4 wv = *(const float4*)(wc + og * (OG * 288) + 4 * q);
            float vv[4] = {wv.x, wv.y, wv.z, wv.w};
            int r0 = 4 * q;
            #pragma unroll
            for (int e = 0; e < 4; ++e) {
                int r    = r0 + e;
                int ol   = r / 288;
                int rr   = r - ol * 288;      // cc*9 + dh*3 + kk
                int cc   = rr / 9;
                int rem2 = rr - cc * 9;
                int dh   = rem2 / 3;
                int kk   = rem2 - dh * 3;
                swc[ol * WSTR + (cc * 3 + dh) * 4 + kk] = vv[e];
            }
        }
    }

    // ---- stage 3: A2 compute t5 and write st5 ----
    #pragma unroll
    for (int k = 0; k < 6; ++k) {
        int idx = tid + k * 256;
        if (idx < 3 * CMID * 15) {
            int r   = idx / (CMID * 15);
            int rem = idx - r * (CMID * 15);
            int cc  = rem / 15;
            int wq  = rem - cc * 15;
            int ws0 = 4 * wq;
            float2 l0 = L0[k], l1 = L1[k];
            float4 m0 = M0[k], m1 = M1[k];
            if (wq == 0)  { l0 = make_float2(0.f, 0.f); l1 = make_float2(0.f, 0.f); }
            if (wq == 14) { m0 = make_float4(0.f, 0.f, 0.f, 0.f);
                            m1 = make_float4(0.f, 0.f, 0.f, 0.f); }
            float t0[6] = {l0.x, l0.y, m0.x, m0.y, m0.z, m0.w};
            float t1[6] = {l1.x, l1.y, m1.x, m1.y, m1.z, m1.w};
            float2 dA = TA[k], dB = TB[k], dC = TC[k];
            float v[4];
            #pragma unroll
            for (int q = 0; q < 4; ++q)
                v[q] = t0[q] * dA.x + t0[q + 1] * dA.y + t0[q + 2] * dB.x
                     + t1[q] * dB.y + t1[q + 1] * dC.x + t1[q + 2] * dC.y;
            if (wq == 0)  v[0] = 0.f;                              // wp = -1
            if (wq == 14) { v[1] = 0.f; v[2] = 0.f; v[3] = 0.f; }  // wp >= 56
            *(float4*)(st5 + (r * CMID + cc) * T5STR + ws0) =
                make_float4(v[0], v[1], v[2], v[3]);
        }
    }
    __syncthreads();

    // ---- phase B: 3x3 conv, 4 ol x 8 w per thread, cc split 8-way by ccq ----
    if (tid < 224) {
        const int ccq  = tid & 7;        // lane bits 0-2 -> shfl_xor reduce
        const int rest = tid >> 3;       // 0..27
        const int olg  = rest / 7;       // 0..3
        const int wt   = rest - olg * 7; // 0..6
        const int w0   = wt * 8;
        const int ol0  = olg * 4;

        float acc[4][8] = {};
        const float* wb = swc + ol0 * WSTR;

        #pragma unroll
        for (int i = 0; i < 4; ++i) {
            int cc = ccq + 8 * i;        // 8 ccq lanes -> 8 distinct 4-bank rows
            #pragma unroll
            for (int dh = 0; dh < 3; ++dh) {
                const float* trow = st5 + (dh * CMID + cc) * T5STR + w0;
                float4 a  = *(const float4*)trow;
                float4 b  = *(const float4*)(trow + 4);
                float2 c2 = *(const float2*)(trow + 8);
                float t[10] = {a.x, a.y, a.z, a.w, b.x, b.y, b.z, b.w, c2.x, c2.y};
                int wi = (cc * 3 + dh) * 4;
                #pragma unroll
                for (int o = 0; o < 4; ++o) {
                    float4 wv = *(const float4*)(wb + o * WSTR + wi);
                    #pragma unroll
                    for (int j = 0; j < 8; ++j)
                        acc[o][j] += t[j] * wv.x + t[j + 1] * wv.y + t[j + 2] * wv.z;
                }
            }
        }

        // reduce the 8 ccq partial sums (lane bits 0-2)
        #pragma unroll
        for (int o = 0; o < 4; ++o)
            #pragma unroll
            for (int j = 0; j < 8; ++j) {
                acc[o][j] += __shfl_xor(acc[o][j], 1);
                acc[o][j] += __shfl_xor(acc[o][j], 2);
                acc[o][j] += __shfl_xor(acc[o][j], 4);
            }

        if (ccq == 0) {
            #pragma unroll
            for (int o = 0; o < 4; ++o) {
                float* p = out + ((og * OG + ol0 + o) * HH + h) * WW + w0;
                *(float4*)(p)     = make_float4(acc[o][0], acc[o][1], acc[o][2], acc[o][3]);
                *(float4*)(p + 4) = make_float4(acc[o][4], acc[o][5], acc[o][6], acc[o][7]);
            }
        }
    }
}

extern "C" void kernel_launch(void* const* d_in, const int* in_sizes, int n_in,
                              void* d_out, int out_size, void* d_ws, size_t ws_size,
                              hipStream_t stream) {
    const float* x  = (const float*)d_in[0];
    const float* wc = (const float*)d_in[1];
    const float* wd = (const float*)d_in[2];
    float* out = (float*)d_out;
    dim3 grid(HH, CIN / OG);  // 56 x 4 = 224 blocks
    fused_dw_sum_conv<<<grid, 256, 0, stream>>>(x, wc, wd, out);
}